// Round 1
// 481.411 us; speedup vs baseline: 1.0105x; 1.0105x over previous
//
#include <hip/hip_runtime.h>
#include <hip/hip_bf16.h>

typedef unsigned short u16;
typedef __bf16 bf16x8 __attribute__((ext_vector_type(8)));
typedef float  f32x4  __attribute__((ext_vector_type(4)));

__device__ __forceinline__ unsigned pk2(float a, float b) {
    __hip_bfloat162 h = __float22bfloat162_rn(make_float2(a, b));
    unsigned u; __builtin_memcpy(&u, &h, 4);
    return u;   // low 16 = bf16(a), high 16 = bf16(b)
}
__device__ __forceinline__ u16 f2b1(float f) { return (u16)(pk2(f, f) & 0xFFFFu); }

#define MFMA __builtin_amdgcn_mfma_f32_16x16x32_bf16

// ---------------------------------------------------------------------------
// prep: ppK[r][j] = (pos_table[r].W_pos_w[j,128:256] + W_pos_b[j]) * 2*log2(e)
//       wb1/wb2: bf16 weights repacked into per-(n,kk) contiguous 1KB tiles:
//       element (row, col) -> [ (row>>4)*4 + (col>>5) ][ row&15 ][ col&31 ]
//       so a wave's 64 B-frag lanes (c,g) read one contiguous 1KB burst.
// ---------------------------------------------------------------------------
__global__ __launch_bounds__(128) void prep_kernel(
    const float* __restrict__ pos_table, const float* __restrict__ Wpw,
    const float* __restrict__ Wpb, const float* __restrict__ W2,
    float* __restrict__ ppK, u16* __restrict__ wb1, u16* __restrict__ wb2)
{
    const int b = blockIdx.x, t = threadIdx.x;
    if (b < 65) {
        const float4* pr = (const float4*)(pos_table + b * 128);
        const float4* wr = (const float4*)(Wpw + t * 256 + 128);
        float acc = Wpb[t];
        #pragma unroll
        for (int k = 0; k < 32; ++k) {
            const float4 p = pr[k], wv = wr[k];
            acc += p.x * wv.x + p.y * wv.y + p.z * wv.z + p.w * wv.w;
        }
        ppK[b * 128 + t] = acc * 2.885390081777927f;   // pre-scaled for exp2
    } else {
        const int j = b - 65;                          // output row 0..127
        // swizzled tile offset for (row j, col t)
        const int off = (((j >> 4) * 4 + (t >> 5)) * 16 + (j & 15)) * 32 + (t & 31);
        wb1[off] = f2b1(Wpw[j * 256 + t]);
        wb2[off] = f2b1(W2[j * 128 + t]);
    }
}

// ---------------------------------------------------------------------------
// fused: one block = TWO sessions (128 token rows x 128 hidden)
// wave w owns rows 32w..32w+31 (2 m-tiles); session of wave = w>>1.
// Weights are NOT LDS-staged: B-frags stream from global (L1/L2-hot, all
// blocks share the same 64KB). LDS 38400 B -> 4 blocks/CU (was 73KB -> 2).
// GEMMs restructured per-n (8 live acc VGPR instead of 64) to fit the
// __launch_bounds__(256,4) 128-VGPR cap for 16 waves/CU.
// ---------------------------------------------------------------------------
__global__ __launch_bounds__(256, 4) void fused_kernel(
    const float* __restrict__ hidden, const int* __restrict__ rpos,
    const float* __restrict__ W1, const float* __restrict__ W1b,
    const float* __restrict__ W2b, const float* __restrict__ qw,
    const float* __restrict__ qb, const float* __restrict__ ppK,
    const u16* __restrict__ wb1g, const u16* __restrict__ wb2g,
    float* __restrict__ out)
{
    // 128 rows x 136 bf16 (pad +8: 272B row stride, bank-spread)
    __shared__ __align__(16) u16 hbf[128 * 136];    // 34816 B (hidden -> ph)
    __shared__ float meanv[256];                    // [2][128] fp32 sums
    __shared__ float g1s[256];                      // [2][128]
    __shared__ float qws[128];
    __shared__ float alphas[128];
    __shared__ int   rps[128];                      // total 38400 B

    const int tid = threadIdx.x;
    const int blk = blockIdx.x;
    const int w = tid >> 6;                 // wave 0..3, rows 32w..32w+31
    const int l = tid & 63;
    const int c = l & 15;                   // MFMA A-row / B-row / D-col
    const int g = l >> 4;                   // quad
    const int R = 32 * w;
    const float* hsrc = hidden + (size_t)blk * (128 * 128);

    // ---- phase 0: zero mean accumulators, stage small vectors
    meanv[tid] = 0.f;
    if (tid < 128) { rps[tid] = rpos[blk * 128 + tid]; qws[tid] = qw[tid]; }
    __syncthreads();

    // ---- phase 1: hidden -> bf16 LDS; fp32 column sums.
    // Thread's 16 chunks hit column group (4*tid)&127; rows (tid>>5)+8i.
    // Lanes l and l^32 share the column group -> fold via shfl, then only
    // half the lanes issue atomics (4-way contention instead of 8-way).
    {
        float4 ms0 = {0.f, 0.f, 0.f, 0.f}, ms1 = {0.f, 0.f, 0.f, 0.f};
        #pragma unroll
        for (int i = 0; i < 16; ++i) {
            const int i4 = tid + i * 256;
            const float4 v = ((const float4*)hsrc)[i4];
            const int e = i4 * 4, row = e >> 7, col = e & 127;
            uint2 st; st.x = pk2(v.x, v.y); st.y = pk2(v.z, v.w);
            *(uint2*)&hbf[row * 136 + col] = st;
            if (i < 8) { ms0.x += v.x; ms0.y += v.y; ms0.z += v.z; ms0.w += v.w; }
            else       { ms1.x += v.x; ms1.y += v.y; ms1.z += v.z; ms1.w += v.w; }
        }
        ms0.x += __shfl_xor(ms0.x, 32, 64); ms0.y += __shfl_xor(ms0.y, 32, 64);
        ms0.z += __shfl_xor(ms0.z, 32, 64); ms0.w += __shfl_xor(ms0.w, 32, 64);
        ms1.x += __shfl_xor(ms1.x, 32, 64); ms1.y += __shfl_xor(ms1.y, 32, 64);
        ms1.z += __shfl_xor(ms1.z, 32, 64); ms1.w += __shfl_xor(ms1.w, 32, 64);
        if ((l & 32) == 0) {
            const int mc = (tid * 4) & 127;
            atomicAdd(&meanv[mc],           ms0.x); atomicAdd(&meanv[mc + 1],       ms0.y);
            atomicAdd(&meanv[mc + 2],       ms0.z); atomicAdd(&meanv[mc + 3],       ms0.w);
            atomicAdd(&meanv[128 + mc],     ms1.x); atomicAdd(&meanv[128 + mc + 1], ms1.y);
            atomicAdd(&meanv[128 + mc + 2], ms1.z); atomicAdd(&meanv[128 + mc + 3], ms1.w);
        }
    }
    __syncthreads();

    // ---- g1[s][col] = mean[s].W1[col] / 64 + W1_b + W2_b   (all 256 threads)
    {
        const int col = tid & 127, s = tid >> 7;
        const float4* wr = (const float4*)(W1 + col * 128);
        const float4* mv = (const float4*)(meanv + s * 128);
        float acc = 0.f;
        #pragma unroll 8
        for (int k4 = 0; k4 < 32; ++k4) {
            const float4 wv = wr[k4], m4 = mv[k4];
            acc += m4.x * wv.x + m4.y * wv.y + m4.z * wv.z + m4.w * wv.w;
        }
        g1s[tid] = W1b[col] + W2b[col] + acc * (1.f / 64.f);
        // consumed after the pre-epilogue barrier below
    }

    // ---- GEMM1 A-frags (hidden, own wave's rows only)
    bf16x8 af[2][4];
    #pragma unroll
    for (int m = 0; m < 2; ++m)
        #pragma unroll
        for (int kk = 0; kk < 4; ++kk)
            af[m][kk] = *(const bf16x8*)&hbf[(R + 16 * m + c) * 136 + kk * 32 + g * 8];

    int pko[2][4];                          // ppK element offsets per (m,r)
    #pragma unroll
    for (int m = 0; m < 2; ++m)
        #pragma unroll
        for (int r = 0; r < 4; ++r)
            pko[m][r] = rps[R + 16 * m + 4 * g + r] * 128 + c;

    // ---- GEMM1 per n-tile: ph = tanh(hidden @ Wpa^T + pp), fused activation.
    // B-frags stream from global swizzled tiles: one 1KB burst per (n,kk).
    {
        const u16* wb1p = wb1g + c * 32 + g * 8;
        const float K2 = 2.885390081777927f;        // 2*log2(e)
        #pragma unroll
        for (int n = 0; n < 8; ++n) {
            f32x4 acc[2] = {};
            #pragma unroll
            for (int kk = 0; kk < 4; ++kk) {
                const bf16x8 bfr = *(const bf16x8*)(wb1p + n * 2048 + kk * 512);
                acc[0] = MFMA(af[0][kk], bfr, acc[0], 0, 0, 0);
                acc[1] = MFMA(af[1][kk], bfr, acc[1], 0, 0, 0);
            }
            #pragma unroll
            for (int m = 0; m < 2; ++m)
                #pragma unroll
                for (int r = 0; r < 4; ++r) {
                    const float arg = fmaf(acc[m][r], K2, ppK[pko[m][r] + 16 * n]);
                    const float e2 = __builtin_amdgcn_exp2f(arg);
                    const float rc = __builtin_amdgcn_rcpf(e2 + 1.f);
                    // in-place over own wave's rows (wave-local, no barrier)
                    hbf[(R + 16 * m + 4 * g + r) * 136 + 16 * n + c] =
                        f2b1(fmaf(-2.f, rc, 1.f));          // tanh
                }
        }
    }

    // ---- GEMM2 A-frags (ph, own rows; same-wave ds order guarantees data)
    bf16x8 af2[2][4];
    #pragma unroll
    for (int m = 0; m < 2; ++m)
        #pragma unroll
        for (int kk = 0; kk < 4; ++kk)
            af2[m][kk] = *(const bf16x8*)&hbf[(R + 16 * m + c) * 136 + kk * 32 + g * 8];

    __syncthreads();    // only cross-wave dep left: g1s (written by all waves)

    // ---- GEMM2 per n-tile: gate = sigmoid(g1 + ph @ W2^T); alpha = gate.qw
    {
        const u16* wb2p = wb2g + c * 32 + g * 8;
        const float K1 = 1.4426950408889634f;       // log2(e)
        const int sw = w >> 1;                      // wave's session
        float prt[2][4] = {};
        #pragma unroll
        for (int n = 0; n < 8; ++n) {
            f32x4 acc[2] = {};
            #pragma unroll
            for (int kk = 0; kk < 4; ++kk) {
                const bf16x8 bfr = *(const bf16x8*)(wb2p + n * 2048 + kk * 512);
                acc[0] = MFMA(af2[0][kk], bfr, acc[0], 0, 0, 0);
                acc[1] = MFMA(af2[1][kk], bfr, acc[1], 0, 0, 0);
            }
            const float gv = -K1 * g1s[sw * 128 + 16 * n + c];
            const float qv = qws[16 * n + c];
            #pragma unroll
            for (int m = 0; m < 2; ++m)
                #pragma unroll
                for (int r = 0; r < 4; ++r) {
                    const float arg = fmaf(acc[m][r], -K1, gv);
                    const float e2 = __builtin_amdgcn_exp2f(arg);
                    const float rc = __builtin_amdgcn_rcpf(e2 + 1.f);   // sigmoid
                    prt[m][r] = fmaf(rc, qv, prt[m][r]);
                }
        }
        #pragma unroll
        for (int msk = 1; msk <= 8; msk <<= 1)
            #pragma unroll
            for (int m = 0; m < 2; ++m)
                #pragma unroll
                for (int r = 0; r < 4; ++r)
                    prt[m][r] += __shfl_xor(prt[m][r], msk, 64);
        if (c == 0) {
            const float qbv = qb[0];
            #pragma unroll
            for (int m = 0; m < 2; ++m)
                #pragma unroll
                for (int r = 0; r < 4; ++r)
                    alphas[R + 16 * m + 4 * g + r] = prt[m][r] + qbv;
        }
    }
    __syncthreads();

    // ---- out[s] = sum_t alpha_t * hidden[t]  (fp32 global, L2/L3-hot;
    //      thread = (session p, column h); coalesced across lanes)
    {
        const int h = tid & 127, p = tid >> 7;
        const float* hs = hsrc + p * (64 * 128) + h;
        float accf = 0.f;
        #pragma unroll 8
        for (int t = 0; t < 64; ++t)
            accf = fmaf(alphas[64 * p + t], hs[t * 128], accf);
        out[(size_t)blk * 256 + tid] = accf;
    }
}

// ---------------------------------------------------------------------------
extern "C" void kernel_launch(void* const* d_in, const int* in_sizes, int n_in,
                              void* d_out, int out_size, void* d_ws, size_t ws_size,
                              hipStream_t stream)
{
    const float* hidden    = (const float*)d_in[0];
    const float* pos_table = (const float*)d_in[1];
    const float* Wpw       = (const float*)d_in[2];
    const float* Wpb       = (const float*)d_in[3];
    const float* W1w       = (const float*)d_in[4];
    const float* W1b       = (const float*)d_in[5];
    const float* W2w       = (const float*)d_in[6];
    const float* W2b       = (const float*)d_in[7];
    const float* qw        = (const float*)d_in[8];
    const float* qb        = (const float*)d_in[9];
    const int*   rpos      = (const int*)d_in[11];
    float* out = (float*)d_out;

    const int B = in_sizes[10];              // sessions (8192)

    // workspace layout (98816 B total)
    char* wsb = (char*)d_ws;
    float* ppK = (float*)wsb;                        // 65*128*4 = 33280
    u16* wb1   = (u16*)(wsb + 33280);                // 32768
    u16* wb2   = (u16*)(wsb + 33280 + 32768);        // 32768

    prep_kernel<<<193, 128, 0, stream>>>(pos_table, Wpw, Wpb, W2w,
                                         ppK, wb1, wb2);
    fused_kernel<<<B / 2, 256, 0, stream>>>(hidden, rpos, W1w, W1b, W2b, qw, qb,
                                            ppK, wb1, wb2, out);
}

// Round 2
// 479.835 us; speedup vs baseline: 1.0138x; 1.0033x over previous
//
#include <hip/hip_runtime.h>
#include <hip/hip_bf16.h>

typedef unsigned short u16;
typedef __bf16 bf16x8 __attribute__((ext_vector_type(8)));
typedef float  f32x4  __attribute__((ext_vector_type(4)));

__device__ __forceinline__ unsigned pk2(float a, float b) {
    __hip_bfloat162 h = __float22bfloat162_rn(make_float2(a, b));
    unsigned u; __builtin_memcpy(&u, &h, 4);
    return u;   // low 16 = bf16(a), high 16 = bf16(b)
}
__device__ __forceinline__ u16 f2b1(float f) { return (u16)(pk2(f, f) & 0xFFFFu); }

#define MFMA __builtin_amdgcn_mfma_f32_16x16x32_bf16

// ---------------------------------------------------------------------------
// prep: ppK[r][j] = (pos_table[r].W_pos_w[j,128:256] + W_pos_b[j]) * 2*log2(e)
//       wb1/wb2: bf16 weights repacked into per-(n,kk) contiguous 1KB tiles:
//       element (row, col) -> [ (row>>4)*4 + (col>>5) ][ row&15 ][ col&31 ]
//       so a wave's 64 B-frag lanes (c,g) read one contiguous 1KB burst.
// ---------------------------------------------------------------------------
__global__ __launch_bounds__(128) void prep_kernel(
    const float* __restrict__ pos_table, const float* __restrict__ Wpw,
    const float* __restrict__ Wpb, const float* __restrict__ W2,
    float* __restrict__ ppK, u16* __restrict__ wb1, u16* __restrict__ wb2)
{
    const int b = blockIdx.x, t = threadIdx.x;
    if (b < 65) {
        const float4* pr = (const float4*)(pos_table + b * 128);
        const float4* wr = (const float4*)(Wpw + t * 256 + 128);
        float acc = Wpb[t];
        #pragma unroll
        for (int k = 0; k < 32; ++k) {
            const float4 p = pr[k], wv = wr[k];
            acc += p.x * wv.x + p.y * wv.y + p.z * wv.z + p.w * wv.w;
        }
        ppK[b * 128 + t] = acc * 2.885390081777927f;   // pre-scaled for exp2
    } else {
        const int j = b - 65;                          // output row 0..127
        // swizzled tile offset for (row j, col t)
        const int off = (((j >> 4) * 4 + (t >> 5)) * 16 + (j & 15)) * 32 + (t & 31);
        wb1[off] = f2b1(Wpw[j * 256 + t]);
        wb2[off] = f2b1(W2[j * 128 + t]);
    }
}

// ---------------------------------------------------------------------------
// fused: one block = TWO sessions (128 token rows x 128 hidden)
// wave w owns rows 32w..32w+31 (2 m-tiles); session of wave = w>>1.
// v2 (this round): R1 proved occupancy is NOT the limit (2x waves, 0% gain,
// all pipes <25%) -> latency-chain bound. So trade occupancy for ILP:
// __launch_bounds__(256,2) gives a 256-VGPR budget; all 32 B-frags per GEMM
// preloaded in one burst (1 L2 round-trip instead of 8 serialized), ppK
// gathers hoisted ahead of the MFMA cluster, epilogue re-read pipelined
// with 8 independent chains. LDS stays 38400 B.
// ---------------------------------------------------------------------------
__global__ __launch_bounds__(256, 2) void fused_kernel(
    const float* __restrict__ hidden, const int* __restrict__ rpos,
    const float* __restrict__ W1, const float* __restrict__ W1b,
    const float* __restrict__ W2b, const float* __restrict__ qw,
    const float* __restrict__ qb, const float* __restrict__ ppK,
    const u16* __restrict__ wb1g, const u16* __restrict__ wb2g,
    float* __restrict__ out)
{
    // 128 rows x 136 bf16 (pad +8: 272B row stride, bank-spread)
    __shared__ __align__(16) u16 hbf[128 * 136];    // 34816 B (hidden -> ph)
    __shared__ float meanv[256];                    // [2][128] fp32 sums
    __shared__ float g1s[256];                      // [2][128]
    __shared__ float qws[128];
    __shared__ float alphas[128];
    __shared__ int   rps[128];                      // total 38400 B

    const int tid = threadIdx.x;
    const int blk = blockIdx.x;
    const int w = tid >> 6;                 // wave 0..3, rows 32w..32w+31
    const int l = tid & 63;
    const int c = l & 15;                   // MFMA A-row / B-row / D-col
    const int g = l >> 4;                   // quad
    const int R = 32 * w;
    const float* hsrc = hidden + (size_t)blk * (128 * 128);

    // ---- phase 0: zero mean accumulators, stage small vectors
    meanv[tid] = 0.f;
    if (tid < 128) { rps[tid] = rpos[blk * 128 + tid]; qws[tid] = qw[tid]; }
    __syncthreads();

    // ---- phase 1: hidden -> bf16 LDS; fp32 column sums.
    // Thread's 16 chunks hit column group (4*tid)&127; rows (tid>>5)+8i.
    // Lanes l and l^32 share the column group -> fold via shfl, then only
    // half the lanes issue atomics (4-way contention instead of 8-way).
    {
        float4 ms0 = {0.f, 0.f, 0.f, 0.f}, ms1 = {0.f, 0.f, 0.f, 0.f};
        #pragma unroll
        for (int i = 0; i < 16; ++i) {
            const int i4 = tid + i * 256;
            const float4 v = ((const float4*)hsrc)[i4];
            const int e = i4 * 4, row = e >> 7, col = e & 127;
            uint2 st; st.x = pk2(v.x, v.y); st.y = pk2(v.z, v.w);
            *(uint2*)&hbf[row * 136 + col] = st;
            if (i < 8) { ms0.x += v.x; ms0.y += v.y; ms0.z += v.z; ms0.w += v.w; }
            else       { ms1.x += v.x; ms1.y += v.y; ms1.z += v.z; ms1.w += v.w; }
        }
        ms0.x += __shfl_xor(ms0.x, 32, 64); ms0.y += __shfl_xor(ms0.y, 32, 64);
        ms0.z += __shfl_xor(ms0.z, 32, 64); ms0.w += __shfl_xor(ms0.w, 32, 64);
        ms1.x += __shfl_xor(ms1.x, 32, 64); ms1.y += __shfl_xor(ms1.y, 32, 64);
        ms1.z += __shfl_xor(ms1.z, 32, 64); ms1.w += __shfl_xor(ms1.w, 32, 64);
        if ((l & 32) == 0) {
            const int mc = (tid * 4) & 127;
            atomicAdd(&meanv[mc],           ms0.x); atomicAdd(&meanv[mc + 1],       ms0.y);
            atomicAdd(&meanv[mc + 2],       ms0.z); atomicAdd(&meanv[mc + 3],       ms0.w);
            atomicAdd(&meanv[128 + mc],     ms1.x); atomicAdd(&meanv[128 + mc + 1], ms1.y);
            atomicAdd(&meanv[128 + mc + 2], ms1.z); atomicAdd(&meanv[128 + mc + 3], ms1.w);
        }
    }
    __syncthreads();

    // ---- g1[s][col] = mean[s].W1[col] / 64 + W1_b + W2_b   (all 256 threads)
    {
        const int col = tid & 127, s = tid >> 7;
        const float4* wr = (const float4*)(W1 + col * 128);
        const float4* mv = (const float4*)(meanv + s * 128);
        float acc = 0.f;
        #pragma unroll 8
        for (int k4 = 0; k4 < 32; ++k4) {
            const float4 wv = wr[k4], m4 = mv[k4];
            acc += m4.x * wv.x + m4.y * wv.y + m4.z * wv.z + m4.w * wv.w;
        }
        g1s[tid] = W1b[col] + W2b[col] + acc * (1.f / 64.f);
        // consumed after the pre-epilogue barrier below
    }

    // ---- GEMM1 A-frags (hidden, own wave's rows only)
    bf16x8 af[2][4];
    #pragma unroll
    for (int m = 0; m < 2; ++m)
        #pragma unroll
        for (int kk = 0; kk < 4; ++kk)
            af[m][kk] = *(const bf16x8*)&hbf[(R + 16 * m + c) * 136 + kk * 32 + g * 8];

    int pko[2][4];                          // ppK element offsets per (m,r)
    #pragma unroll
    for (int m = 0; m < 2; ++m)
        #pragma unroll
        for (int r = 0; r < 4; ++r)
            pko[m][r] = rps[R + 16 * m + 4 * g + r] * 128 + c;

    // ---- GEMM1: ph = tanh(hidden @ Wpa^T + pp), fused activation.
    // All 32 B-frags preloaded in one burst (128 VGPR): single L2 round-trip.
    {
        const u16* wb1p = wb1g + c * 32 + g * 8;
        bf16x8 bf[8][4];
        #pragma unroll
        for (int n = 0; n < 8; ++n)
            #pragma unroll
            for (int kk = 0; kk < 4; ++kk)
                bf[n][kk] = *(const bf16x8*)(wb1p + n * 2048 + kk * 512);
        const float K2 = 2.885390081777927f;        // 2*log2(e)
        #pragma unroll
        for (int n = 0; n < 8; ++n) {
            // ppK gathers for this n-tile issued ahead of the MFMA cluster
            float ppv[2][4];
            #pragma unroll
            for (int m = 0; m < 2; ++m)
                #pragma unroll
                for (int r = 0; r < 4; ++r)
                    ppv[m][r] = ppK[pko[m][r] + 16 * n];
            f32x4 acc[2] = {};
            #pragma unroll
            for (int kk = 0; kk < 4; ++kk) {
                acc[0] = MFMA(af[0][kk], bf[n][kk], acc[0], 0, 0, 0);
                acc[1] = MFMA(af[1][kk], bf[n][kk], acc[1], 0, 0, 0);
            }
            #pragma unroll
            for (int m = 0; m < 2; ++m)
                #pragma unroll
                for (int r = 0; r < 4; ++r) {
                    const float arg = fmaf(acc[m][r], K2, ppv[m][r]);
                    const float e2 = __builtin_amdgcn_exp2f(arg);
                    const float rc = __builtin_amdgcn_rcpf(e2 + 1.f);
                    // in-place over own wave's rows (wave-local, no barrier)
                    hbf[(R + 16 * m + 4 * g + r) * 136 + 16 * n + c] =
                        f2b1(fmaf(-2.f, rc, 1.f));          // tanh
                }
        }
    }

    // ---- GEMM2 A-frags (ph, own rows; same-wave ds order guarantees data)
    bf16x8 af2[2][4];
    #pragma unroll
    for (int m = 0; m < 2; ++m)
        #pragma unroll
        for (int kk = 0; kk < 4; ++kk)
            af2[m][kk] = *(const bf16x8*)&hbf[(R + 16 * m + c) * 136 + kk * 32 + g * 8];

    // GEMM2 B-frag burst issued BEFORE the barrier: flies during barrier wait
    bf16x8 bf2[8][4];
    {
        const u16* wb2p = wb2g + c * 32 + g * 8;
        #pragma unroll
        for (int n = 0; n < 8; ++n)
            #pragma unroll
            for (int kk = 0; kk < 4; ++kk)
                bf2[n][kk] = *(const bf16x8*)(wb2p + n * 2048 + kk * 512);
    }

    __syncthreads();    // only cross-wave dep left: g1s (written by all waves)

    // ---- GEMM2: gate = sigmoid(g1 + ph @ W2^T); alpha = gate.qw + qb
    {
        const float K1 = 1.4426950408889634f;       // log2(e)
        const int sw = w >> 1;                      // wave's session
        float prt[2][4] = {};
        #pragma unroll
        for (int n = 0; n < 8; ++n) {
            f32x4 acc[2] = {};
            #pragma unroll
            for (int kk = 0; kk < 4; ++kk) {
                acc[0] = MFMA(af2[0][kk], bf2[n][kk], acc[0], 0, 0, 0);
                acc[1] = MFMA(af2[1][kk], bf2[n][kk], acc[1], 0, 0, 0);
            }
            const float gv = -K1 * g1s[sw * 128 + 16 * n + c];
            const float qv = qws[16 * n + c];
            #pragma unroll
            for (int m = 0; m < 2; ++m)
                #pragma unroll
                for (int r = 0; r < 4; ++r) {
                    const float arg = fmaf(acc[m][r], -K1, gv);
                    const float e2 = __builtin_amdgcn_exp2f(arg);
                    const float rc = __builtin_amdgcn_rcpf(e2 + 1.f);   // sigmoid
                    prt[m][r] = fmaf(rc, qv, prt[m][r]);
                }
        }
        #pragma unroll
        for (int msk = 1; msk <= 8; msk <<= 1)
            #pragma unroll
            for (int m = 0; m < 2; ++m)
                #pragma unroll
                for (int r = 0; r < 4; ++r)
                    prt[m][r] += __shfl_xor(prt[m][r], msk, 64);
        if (c == 0) {
            const float qbv = qb[0];
            #pragma unroll
            for (int m = 0; m < 2; ++m)
                #pragma unroll
                for (int r = 0; r < 4; ++r)
                    alphas[R + 16 * m + 4 * g + r] = prt[m][r] + qbv;
        }
    }
    __syncthreads();

    // ---- out[s] = sum_t alpha_t * hidden[t]  (fp32 global, L2-hot).
    // 8 independent FMA chains, loads batched 8-wide for MLP depth.
    {
        const int h = tid & 127, p = tid >> 7;
        const float* hs = hsrc + p * (64 * 128) + h;
        float a8[8];
        #pragma unroll
        for (int j = 0; j < 8; ++j) a8[j] = 0.f;
        #pragma unroll
        for (int t0 = 0; t0 < 8; ++t0) {
            float v[8], al[8];
            #pragma unroll
            for (int j = 0; j < 8; ++j) {
                v[j]  = hs[(t0 * 8 + j) * 128];
                al[j] = alphas[64 * p + t0 * 8 + j];
            }
            #pragma unroll
            for (int j = 0; j < 8; ++j) a8[j] = fmaf(al[j], v[j], a8[j]);
        }
        const float accf = ((a8[0] + a8[1]) + (a8[2] + a8[3]))
                         + ((a8[4] + a8[5]) + (a8[6] + a8[7]));
        out[(size_t)blk * 256 + tid] = accf;
    }
}

// ---------------------------------------------------------------------------
extern "C" void kernel_launch(void* const* d_in, const int* in_sizes, int n_in,
                              void* d_out, int out_size, void* d_ws, size_t ws_size,
                              hipStream_t stream)
{
    const float* hidden    = (const float*)d_in[0];
    const float* pos_table = (const float*)d_in[1];
    const float* Wpw       = (const float*)d_in[2];
    const float* Wpb       = (const float*)d_in[3];
    const float* W1w       = (const float*)d_in[4];
    const float* W1b       = (const float*)d_in[5];
    const float* W2w       = (const float*)d_in[6];
    const float* W2b       = (const float*)d_in[7];
    const float* qw        = (const float*)d_in[8];
    const float* qb        = (const float*)d_in[9];
    const int*   rpos      = (const int*)d_in[11];
    float* out = (float*)d_out;

    const int B = in_sizes[10];              // sessions (8192)

    // workspace layout (98816 B total)
    char* wsb = (char*)d_ws;
    float* ppK = (float*)wsb;                        // 65*128*4 = 33280
    u16* wb1   = (u16*)(wsb + 33280);                // 32768
    u16* wb2   = (u16*)(wsb + 33280 + 32768);        // 32768

    prep_kernel<<<193, 128, 0, stream>>>(pos_table, Wpw, Wpb, W2w,
                                         ppK, wb1, wb2);
    fused_kernel<<<B / 2, 256, 0, stream>>>(hidden, rpos, W1w, W1b, W2b, qw, qb,
                                            ppK, wb1, wb2, out);
}